// Round 1
// baseline (454.676 us; speedup 1.0000x reference)
//
#include <hip/hip_runtime.h>

// 9x9 local-max peak detection (threshold 0.5) on 8192x8192 fp32.
//
// Key identity: threshold t(x)=x*[x>0.5] commutes with max (monotone), so
//   conf[r][c] = (M > 0.5 && M == raw[r][c]) ? M : 0,  M = 9x9 raw max.
// 0-padding is equivalent to -inf padding: a pad value can only win the max
// when everything is <= 0, and then the >0.5 gate kills it anyway.
//
// Streaming structure (no LDS, no barriers):
//   wave = 256-col band (lane owns 4 cols via float4), rolls over 64 output
//   rows. Per input row: 3 overlapping float4 loads (L1 serves the +-16B
//   shifts), horizontal 9-max via shared-prefix, 9-deep register ring,
//   vertical 9-max, predicate, coalesced float4 store. Unroll-by-9 keeps all
//   ring indices compile-time-static (registers, no spills, no v_movs).
//
// NEW this round — serpentine sweeps + NT stores:
//   Odd global strips sweep bottom-up. Each pair of strips sharing an 8-row
//   halo now touches those rows at the SAME time (both at sweep-end for
//   (even,odd) pairs on the same CU; both at sweep-start for (odd,even)
//   pairs, which land on the same XCD since block-id delta = gridDim.x = 32
//   ≡ 0 mod 8). Halo rows become L1/L2 hits instead of HBM re-fetches,
//   removing the 9/8 read overfetch. Output stores are nontemporal so the
//   268 MB write stream doesn't evict the halo window from L2.

#define W 8192
#define H 8192
#define THRESH 0.5f

typedef float v4f __attribute__((ext_vector_type(4)));

__device__ __forceinline__ v4f ld4(const float* __restrict__ in, int r, int c) {
    v4f v = {0.f, 0.f, 0.f, 0.f};
    if ((unsigned)c < (unsigned)W) {
        v = *(const v4f*)(in + (size_t)r * W + c);
    }
    return v;
}

__global__ __launch_bounds__(256, 4) void peak_stream(const float* __restrict__ in,
                                                      float* __restrict__ out) {
    const int lane  = threadIdx.x;                      // 0..63
    const int col0  = blockIdx.x * 256 + lane * 4;      // this lane's 4 cols
    const int strip = blockIdx.y * 4 + threadIdx.y;     // global 64-row strip id
    const int r0    = strip * 64;                       // strip's first output row

    v4f hm[9];   // ring: horizontal 9-max of the last 9 input rows
    v4f ce[9];   // ring: raw center values (delayed 4 rows for the compare)

    // One input row: k = ring slot (compile-time const), rin = input row,
    // rout = output row produced when emit (center of the 9-row window).
    auto dorow = [&](int rin, int rout, int k, bool emit) {
        v4f l = {0.f, 0.f, 0.f, 0.f}, v = l, r = l;
        if ((unsigned)rin < (unsigned)H) {
            l = ld4(in, rin, col0 - 4);
            v = ld4(in, rin, col0);
            r = ld4(in, rin, col0 + 4);
        }
        // L = [l.x l.y l.z l.w v.x v.y v.z v.w r.x r.y r.z r.w]; out j = max L[j..j+8]
        const float common = fmaxf(fmaxf(fmaxf(l.w, v.x), fmaxf(v.y, v.z)),
                                   fmaxf(v.w, r.x));     // max L[3..8]
        const float m12  = fmaxf(l.y, l.z);
        const float m910 = fmaxf(r.y, r.z);
        v4f o;
        o.x = fmaxf(common, fmaxf(l.x, m12));
        o.y = fmaxf(common, fmaxf(m12, r.y));
        o.z = fmaxf(common, fmaxf(l.z, m910));
        o.w = fmaxf(common, fmaxf(m910, r.w));
        hm[k] = o;
        ce[k] = v;
        if (emit) {
            v4f m = hm[0];
#pragma unroll
            for (int j = 1; j < 9; ++j) {
                m.x = fmaxf(m.x, hm[j].x);
                m.y = fmaxf(m.y, hm[j].y);
                m.z = fmaxf(m.z, hm[j].z);
                m.w = fmaxf(m.w, hm[j].w);
            }
            const v4f c4 = ce[(k + 5) % 9];  // raw value at the window-center row
            v4f ov;
            ov.x = (m.x > THRESH && m.x == c4.x) ? m.x : 0.f;
            ov.y = (m.y > THRESH && m.y == c4.y) ? m.y : 0.f;
            ov.z = (m.z > THRESH && m.z == c4.z) ? m.z : 0.f;
            ov.w = (m.w > THRESH && m.w == c4.w) ? m.w : 0.f;
            __builtin_nontemporal_store(ov, (v4f*)(out + (size_t)rout * W + col0));
        }
    };

    if ((strip & 1) == 0) {
        // Even strip: sweep DOWN. Input rows r0-4 .. r0+67; emit rout = rin-4.
#pragma unroll
        for (int t = 0; t < 9; ++t) {
            dorow(r0 - 4 + t, r0 - 8 + t, t, t >= 8);
        }
        for (int tc = 9; tc < 72; tc += 9) {
#pragma unroll
            for (int k = 0; k < 9; ++k) {
                dorow(r0 - 4 + tc + k, r0 - 8 + tc + k, k, true);
            }
        }
    } else {
        // Odd strip: sweep UP. Input rows r0+67 .. r0-4; emit rout = rin+4.
        // The 9x9 max is vertically symmetric, so the ring arithmetic is
        // identical — only the row sequence is reversed.
#pragma unroll
        for (int t = 0; t < 9; ++t) {
            dorow(r0 + 67 - t, r0 + 71 - t, t, t >= 8);
        }
        for (int tc = 9; tc < 72; tc += 9) {
#pragma unroll
            for (int k = 0; k < 9; ++k) {
                dorow(r0 + 67 - tc - k, r0 + 71 - tc - k, k, true);
            }
        }
    }
}

extern "C" void kernel_launch(void* const* d_in, const int* in_sizes, int n_in,
                              void* d_out, int out_size, void* d_ws, size_t ws_size,
                              hipStream_t stream) {
    const float* in = (const float*)d_in[0];
    float* out = (float*)d_out;
    dim3 grid(W / 256, H / 256);        // 32 x 32 blocks
    dim3 block(64, 4, 1);               // 4 waves; wave ty handles strip 4*by+ty
    peak_stream<<<grid, block, 0, stream>>>(in, out);
}